// Round 16
// baseline (210.855 us; speedup 1.0000x reference)
//
#include <hip/hip_runtime.h>
#include <hip/hip_cooperative_groups.h>

namespace cg = cooperative_groups;

typedef __attribute__((ext_vector_type(8))) short bf16x8;
typedef __attribute__((ext_vector_type(4))) float f32x4;

namespace {
constexpr int Bn = 8, Cn = 64, On = 64, Hn = 112, Wn = 112;
constexpr long CONV_ELEMS = (long)Bn * On * Hn * Wn;     // 6422528
constexpr int HP = 114, WP = 114;                        // padded dims (halo)
constexpr long XT_ELEMS = (long)Bn * HP * WP * Cn;       // 6653952
constexpr size_t WB2_BYTES = 4 * 18 * 64 * 8 * 2;        // 73728 (hi-only)
constexpr size_t NEED_WS = (size_t)XT_ELEMS * 2 + WB2_BYTES;
constexpr int HIST_N = Cn * 10;
constexpr int HALO_PER_B = 2 * WP * Cn + 2 * Hn * Cn;    // 28928
constexpr int HALO_ELEMS = Bn * HALO_PER_B;              // 231424
constexpr int INT_BLOCKS = Bn * Hn * 2;                  // 1792
constexpr int HALO_BLOCKS = (HALO_ELEMS + 255) / 256;    // 904
constexpr int WSETUP_BLOCKS = 64;
constexpr int PREP_GRID = WSETUP_BLOCKS + INT_BLOCKS + HALO_BLOCKS;   // 2760
constexpr int CONV_BLOCKS = Bn * 98;                     // 784
constexpr int HIST_BLOCKS = Bn * Cn;                     // 512
constexpr int MAIN_GRID = CONV_BLOCKS + HIST_BLOCKS;     // 1296 (5.06 blocks/CU)
}

__device__ __forceinline__ ushort f2bf(float v) {        // RNE float->bf16 bits
    unsigned u = __float_as_uint(v);
    return (ushort)((u + 0x7fffu + ((u >> 16) & 1u)) >> 16);
}

// ---------------- prep unit: [0,64) wb2+hist-zero | interior | halo ----------------
__device__ __forceinline__ void prep_unit(
    int bx, int tid, char* smem,
    const float* __restrict__ x, const float* __restrict__ wt,
    ushort* __restrict__ xh, ushort* __restrict__ wb2, float* __restrict__ hist)
{
    if (bx < WSETUP_BLOCKS) {
        // wb2 flat = ((g*18+k)*64+lane)*8+j : oc-group g, k-step k, lane -> its
        // exact MFMA B-fragment. HI ONLY (r12: error budget ~0.09 >> added ~6e-3).
        const int bw = bx;
        for (int i = tid; i < 576; i += 256) {
            int flat = bw * 576 + i;
            int g = flat / 9216;                  // 18*64*8
            int rem = flat - g * 9216;
            int k = rem >> 9;
            int rem2 = rem & 511;
            int lane = rem2 >> 3, j = rem2 & 7;
            int kk = k * 32 + (lane >> 4) * 8 + j;
            int kp = kk >> 6, cc = kk & 63;
            wb2[flat] = f2bf(wt[((g * 16 + (lane & 15)) * Cn + cc) * 9 + kp]);
        }
        if (bw == 0)
            for (int i = tid; i < HIST_N; i += 256) hist[i] = 0.0f;
        return;
    }
    int bx2 = bx - WSETUP_BLOCKS;
    if (bx2 < INT_BLOCKS) {          // x (NCHW fp32) -> xh [b][h+1][w+1][c] bf16
        auto ls = reinterpret_cast<float(*)[57]>(smem);   // [64][57]
        const int b = bx2 / 224;
        const int rem = bx2 - b * 224;
        const int h = rem >> 1;
        const int w0 = (rem & 1) * 56;
        for (int i = tid; i < 64 * 56; i += 256) {
            int c = i / 56, w = i - c * 56;
            ls[c][w] = x[(((long)b * Cn + c) * Hn + h) * Wn + w0 + w];
        }
        __syncthreads();
        for (int i = tid; i < 56 * 64; i += 256) {
            int w = i >> 6, c = i & 63;
            xh[(((long)b * HP + h + 1) * WP + (w0 + w + 1)) * 64 + c] = f2bf(ls[c][w]);
        }
        return;
    }
    bx2 -= INT_BLOCKS;               // halo-zero
    int idx = bx2 * 256 + tid;
    if (idx < HALO_ELEMS) {
        int b = idx / HALO_PER_B;
        int r = idx - b * HALO_PER_B;
        int h, w, cc;
        if (r < WP * Cn)                    { h = 0;      w = r / Cn;               cc = r & 63; }
        else if (r < 2 * WP * Cn)           { int q = r - WP * Cn; h = HP - 1; w = q / Cn; cc = q & 63; }
        else if (r < 2 * WP * Cn + Hn * Cn) { int q = r - 2 * WP * Cn; h = 1 + q / Cn; w = 0; cc = q & 63; }
        else                                { int q = r - 2 * WP * Cn - Hn * Cn; h = 1 + q / Cn; w = WP - 1; cc = q & 63; }
        xh[((long)(b * HP + h) * WP + w) * 64 + cc] = 0;
    }
}

// ---------------- conv unit (r12/r15 verified body) ----------------
__device__ __forceinline__ void conv_unit(
    int bx, int tid, char* smem,
    const ushort* __restrict__ xh, const ushort* __restrict__ wb2,
    const float* __restrict__ bias, float* __restrict__ out)
{
    ushort* xs = (ushort*)smem;                   // 10*18 rows * 128 B
    int bid = bx;
    bid = (bid & 7) * 98 + (bid >> 3);            // XCD swizzle (784 % 8 == 0)
    const int b = bid / 98;
    const int t = bid - b * 98;
    const int h0 = (t / 7) * 8, w0 = (t % 7) * 16;
    const int lane = tid & 63, wvi = tid >> 6;
    const int l15 = lane & 15, lg = lane >> 4;
    const int pxh = wvi >> 1, och = wvi & 1;

    // stage 1440 16-B chunks: physical chunk p holds logical p ^ (wl&7)
    const ushort* xbase = xh + (long)((b * HP + h0) * WP + w0) * 64;
#pragma unroll
    for (int it = 0; it < 6; ++it) {
        int F = it * 256 + tid;
        if (F < 1440) {
            int R = F >> 3, p = F & 7;
            int hl = R / 18, wl = R - hl * 18;
            bf16x8 v = *(const bf16x8*)(xbase + (hl * WP + wl) * 64 + (p ^ (wl & 7)) * 8);
            *(bf16x8*)(xs + F * 8) = v;
        }
    }
    __syncthreads();

    const ushort* Bw0 = wb2 + (((och * 2 + 0) * 1152 + lane) << 3);  // 1152=18*64
    const ushort* Bw1 = wb2 + (((och * 2 + 1) * 1152 + lane) << 3);
    f32x4 acc[4][2];
#pragma unroll
    for (int a = 0; a < 4; ++a)
#pragma unroll
        for (int j = 0; j < 2; ++j) acc[a][j] = (f32x4){0.f, 0.f, 0.f, 0.f};

    auto lda = [&](int k, bf16x8* A) {
        int kp = k >> 1, ch = k & 1;
        int dh = kp / 3, dw = kp - 3 * dh;
        int wl = l15 + dw;
        int rowb = pxh * 9216 + dh * 2304 + wl * 128;
        int colb = ((lg + 4 * ch) << 4) ^ ((wl & 7) << 4);
#pragma unroll
        for (int a = 0; a < 4; ++a)
            A[a] = *(const bf16x8*)((const char*)xs + a * 2304 + rowb + colb);
    };

    bf16x8 AX[4], AY[4], BX0, BX1, BY0, BY1;
    lda(0, AX);
    BX0 = *(const bf16x8*)(Bw0 + 0 * 512);
    BX1 = *(const bf16x8*)(Bw1 + 0 * 512);

#pragma unroll 1
    for (int t2 = 0; t2 < 9; ++t2) {
        BY0 = *(const bf16x8*)(Bw0 + (2 * t2 + 1) * 512);
        BY1 = *(const bf16x8*)(Bw1 + (2 * t2 + 1) * 512);
        lda(2 * t2 + 1, AY);
#pragma unroll
        for (int a = 0; a < 4; ++a)
            acc[a][0] = __builtin_amdgcn_mfma_f32_16x16x32_bf16(AX[a], BX0, acc[a][0], 0, 0, 0);
#pragma unroll
        for (int a = 0; a < 4; ++a)
            acc[a][1] = __builtin_amdgcn_mfma_f32_16x16x32_bf16(AX[a], BX1, acc[a][1], 0, 0, 0);
        const int kn = (t2 < 8) ? 2 * t2 + 2 : 17;
        BX0 = *(const bf16x8*)(Bw0 + kn * 512);
        BX1 = *(const bf16x8*)(Bw1 + kn * 512);
        lda(kn, AX);
#pragma unroll
        for (int a = 0; a < 4; ++a)
            acc[a][0] = __builtin_amdgcn_mfma_f32_16x16x32_bf16(AY[a], BY0, acc[a][0], 0, 0, 0);
#pragma unroll
        for (int a = 0; a < 4; ++a)
            acc[a][1] = __builtin_amdgcn_mfma_f32_16x16x32_bf16(AY[a], BY1, acc[a][1], 0, 0, 0);
    }

    // D mapping: col(lane&15)=oc, row=(lane>>4)*4+reg = w-offset
#pragma unroll
    for (int j = 0; j < 2; ++j) {
        const int oc = och * 32 + j * 16 + l15;
        const float bv = bias[oc];
#pragma unroll
        for (int a = 0; a < 4; ++a) {
            const int hr = h0 + pxh * 4 + a;
            float4 st = {acc[a][j].x + bv, acc[a][j].y + bv,
                         acc[a][j].z + bv, acc[a][j].w + bv};
            *reinterpret_cast<float4*>(
                out + (((long)b * On + oc) * Hn + hr) * Wn + w0 + lg * 4) = st;
        }
    }
}

// ---------------- hist unit (r14/r15 register-mask body) ----------------
__device__ __forceinline__ void hist_unit(
    int hb, int tid, char* smem,
    const float* __restrict__ x, const float* __restrict__ wt,
    float* __restrict__ hist)
{
    unsigned* exm  = reinterpret_cast<unsigned*>(smem);          // [64]
    int*      meta = reinterpret_cast<int*>(smem + 256);         // n0, anyEx
    unsigned* wsum = reinterpret_cast<unsigned*>(smem + 264);    // [4][5]
    unsigned* corr = reinterpret_cast<unsigned*>(smem + 352);    // [10]
    const int b = hb >> 6, c = hb & 63;
    if (tid < 10) corr[tid] = 0u;
    if (tid < 64) {                           // wave 0: weight-zero scan for c
        unsigned m = 0;
#pragma unroll
        for (int kp = 0; kp < 9; ++kp)
            if (wt[(tid * Cn + c) * 9 + kp] == 0.0f) m |= 1u << kp;
        exm[tid] = m;
        unsigned long long nz = __ballot(m == 0u);
        if (tid == 0) { meta[0] = (int)__popcll(nz); meta[1] = (nz != ~0ull); }
    }
    __syncthreads();

    const int h = tid >> 7;                   // waves 0,1 -> h=0; 2,3 -> h=1
    const int r = tid & 127;                  // row (active if < 112)
    unsigned pk0 = 0, pk1 = 0;                // bins 0-4 / 5-9, 6-bit fields
    if (r < Hn) {
        const float* xp = x + ((long)b * Cn + c) * (Hn * Wn);
        auto rowmask = [&](int row) -> unsigned long long {
            if ((unsigned)row >= (unsigned)Hn) return (1ull << 58) - 1ull;
            const float* rp = xp + row * Wn;
            unsigned long long m;
            if (h == 0) {
                m = 1ull;                     // col -1 pad (bit 0)
#pragma unroll
                for (int q = 0; q < 14; ++q) {
                    float4 v = *(const float4*)(rp + 4 * q);
                    unsigned nib = (unsigned)(v.x == 0.0f) | ((unsigned)(v.y == 0.0f) << 1)
                                 | ((unsigned)(v.z == 0.0f) << 2) | ((unsigned)(v.w == 0.0f) << 3);
                    m |= (unsigned long long)nib << (4 * q + 1);
                }
                m |= (unsigned long long)(rp[56] == 0.0f) << 57;
            } else {
                m = (rp[55] == 0.0f) ? 1ull : 0ull;   // col 55 (bit 0)
#pragma unroll
                for (int q = 0; q < 14; ++q) {
                    float4 v = *(const float4*)(rp + 56 + 4 * q);
                    unsigned nib = (unsigned)(v.x == 0.0f) | ((unsigned)(v.y == 0.0f) << 1)
                                 | ((unsigned)(v.z == 0.0f) << 2) | ((unsigned)(v.w == 0.0f) << 3);
                    m |= (unsigned long long)nib << (4 * q + 1);
                }
                m |= 1ull << 57;              // col 112 pad
            }
            return m;
        };
        unsigned long long Tm = rowmask(r - 1);
        unsigned long long Mm = rowmask(r);
        unsigned long long Bm = rowmask(r + 1);
#pragma unroll
        for (int i = 0; i < 56; ++i) {
            int z = __popc((unsigned)(Tm >> i) & 7u) + __popc((unsigned)(Mm >> i) & 7u)
                  + __popc((unsigned)(Bm >> i) & 7u);
            if (z < 5) pk0 += 1u << (6 * z); else pk1 += 1u << (6 * (z - 5));
        }
        if (meta[1]) {                        // exact-zero weights (never taken)
            for (int i = 0; i < 56; ++i) {
                unsigned m9 = ((unsigned)(Tm >> i) & 7u)
                            | (((unsigned)(Mm >> i) & 7u) << 3)
                            | (((unsigned)(Bm >> i) & 7u) << 6);
                for (int oc = 0; oc < 64; ++oc)
                    if (exm[oc]) atomicAdd(&corr[__popc(m9 | exm[oc])], 1u);
            }
        }
    }
    // 6-bit fields -> 5 u32 of 2x16-bit fields, wave shuffle-reduce
    unsigned s0 = (pk0 & 63u)       | ((pk0 >> 6 & 63u) << 16);
    unsigned s1 = (pk0 >> 12 & 63u) | ((pk0 >> 18 & 63u) << 16);
    unsigned s2 = (pk0 >> 24 & 63u) | ((pk1 & 63u) << 16);
    unsigned s3 = (pk1 >> 6 & 63u)  | ((pk1 >> 12 & 63u) << 16);
    unsigned s4 = (pk1 >> 18 & 63u) | ((pk1 >> 24 & 63u) << 16);
#pragma unroll
    for (int l = 1; l < 64; l <<= 1) {
        s0 += __shfl_xor(s0, l); s1 += __shfl_xor(s1, l);
        s2 += __shfl_xor(s2, l); s3 += __shfl_xor(s3, l);
        s4 += __shfl_xor(s4, l);
    }
    const int wv = tid >> 6;
    if ((tid & 63) == 0) {
        wsum[wv * 5 + 0] = s0; wsum[wv * 5 + 1] = s1; wsum[wv * 5 + 2] = s2;
        wsum[wv * 5 + 3] = s3; wsum[wv * 5 + 4] = s4;
    }
    __syncthreads();
    if (tid < 10) {
        unsigned tot = 0;
#pragma unroll
        for (int w2 = 0; w2 < 4; ++w2)
            tot += (wsum[w2 * 5 + (tid >> 1)] >> ((tid & 1) * 16)) & 0xffffu;
        atomicAdd(&hist[c * 10 + tid], (float)(tot * (unsigned)meta[0] + corr[tid]));
    }
}

// ======== fused cooperative kernel: prep (grid-stride) -> grid.sync -> main ========
__global__ __launch_bounds__(256, 6) void fused_kernel(
    const float* __restrict__ x, const float* __restrict__ wt,
    ushort* __restrict__ xh, ushort* __restrict__ wb2,
    const float* __restrict__ bias, float* __restrict__ out,
    float* __restrict__ hist)
{
    __shared__ __align__(16) char smem[23040];
    const int tid = threadIdx.x;
    for (int u = (int)blockIdx.x; u < PREP_GRID; u += (int)gridDim.x) {
        prep_unit(u, tid, smem, x, wt, xh, wb2, hist);
        __syncthreads();
    }
    cg::this_grid().sync();                       // xh/wb2/hist-zero visible
    if ((int)blockIdx.x < CONV_BLOCKS)
        conv_unit((int)blockIdx.x, tid, smem, xh, wb2, bias, out);
    else
        hist_unit((int)blockIdx.x - CONV_BLOCKS, tid, smem, x, wt, hist);
}

// ======== fallback #1: r15 two-kernel path (if cooperative launch fails) ========
__global__ __launch_bounds__(256) void prep_kernel(
    const float* __restrict__ x, const float* __restrict__ wt,
    ushort* __restrict__ xh, ushort* __restrict__ wb2, float* __restrict__ hist)
{
    __shared__ __align__(16) char smem[14592];
    prep_unit((int)blockIdx.x, threadIdx.x, smem, x, wt, xh, wb2, hist);
}

__global__ __launch_bounds__(256, 6) void conv_kernel(
    const ushort* __restrict__ xh, const ushort* __restrict__ wb2,
    const float* __restrict__ bias, const float* __restrict__ x,
    const float* __restrict__ wt, float* __restrict__ out, float* __restrict__ hist)
{
    __shared__ __align__(16) char smem[23040];
    if ((int)blockIdx.x < CONV_BLOCKS)
        conv_unit((int)blockIdx.x, threadIdx.x, smem, xh, wb2, bias, out);
    else
        hist_unit((int)blockIdx.x - CONV_BLOCKS, threadIdx.x, smem, x, wt, hist);
}

// ---------------- fallback #2 (fp32, round-2) — only if ws too small ----------------
namespace fb {
constexpr int TH = 8, TW = 16, CC = 8, NCH = Cn / CC;
constexpr int XROWS = TH + 2, XCOLS = TW + 2, XSTR = 20, WPAD = 68;
}
__global__ void setup_fb_kernel(const float* __restrict__ wt, float* __restrict__ hist,
                                int* __restrict__ n0, int* __restrict__ exCnt,
                                int* __restrict__ exMask) {
    int c = threadIdx.x;
    if (c >= Cn) return;
    int cnt0 = 0, ce = 0;
    for (int oc = 0; oc < On; ++oc) {
        unsigned m = 0;
        const float* wp = wt + (oc * Cn + c) * 9;
        for (int k = 0; k < 9; ++k)
            if (wp[k] == 0.0f) m |= (1u << k);
        if (m == 0u) ++cnt0;
        else exMask[c * 64 + (ce++)] = (int)m;
    }
    n0[c] = cnt0;
    exCnt[c] = ce;
    for (int j = 0; j < 10; ++j) hist[c * 10 + j] = 0.0f;
}
__global__ __launch_bounds__(256, 4) void conv_hist_kernel(
    const float* __restrict__ x, const float* __restrict__ wt,
    const float* __restrict__ bias, float* __restrict__ out,
    float* __restrict__ hist, const int* __restrict__ n0,
    const int* __restrict__ exCnt, const int* __restrict__ exMask)
{
    using namespace fb;
    __shared__ __align__(16) float xs[CC][XROWS][XSTR];
    __shared__ __align__(16) float ws[CC][9][WPAD];
    __shared__ unsigned hist_s[HIST_N];
    const int tid = threadIdx.x;
    const int bx = blockIdx.x;
    const int b = bx / 98;
    const int tt = bx - b * 98;
    const int h0 = (tt / 7) * TH;
    const int w0 = (tt % 7) * TW;
    const int ocg = tid >> 4, pg = tid & 15;
    const int prow = pg >> 1, pcol = (pg & 1) * 8;
    float acc[4][8];
#pragma unroll
    for (int o = 0; o < 4; ++o)
#pragma unroll
        for (int p = 0; p < 8; ++p) acc[o][p] = 0.0f;
    for (int i = tid; i < HIST_N; i += 256) hist_s[i] = 0u;
#pragma unroll 1
    for (int cc = 0; cc < NCH; ++cc) {
        const int cbase = cc * CC;
        __syncthreads();
#pragma unroll 1
        for (int i = tid; i < CC * XROWS * XCOLS; i += 256) {
            int c = i / (XROWS * XCOLS);
            int r = (i - c * XROWS * XCOLS) / XCOLS;
            int cl = i - c * XROWS * XCOLS - r * XCOLS;
            int gr = h0 - 1 + r, gc = w0 - 1 + cl;
            float v = 0.0f;
            if ((unsigned)gr < (unsigned)Hn && (unsigned)gc < (unsigned)Wn)
                v = x[(((long)b * Cn + cbase + c) * Hn + gr) * Wn + gc];
            xs[c][r][cl] = v;
        }
#pragma unroll 1
        for (int i = tid; i < On * CC * 9; i += 256) {
            int oc = i / (CC * 9);
            int j = i - oc * (CC * 9);
            int c = j / 9;
            int k = j - c * 9;
            ws[c][k][oc] = wt[(oc * Cn + cbase + c) * 9 + k];
        }
        __syncthreads();
#pragma unroll 1
        for (int c = 0; c < CC; ++c) {
#pragma unroll
            for (int kh = 0; kh < 3; ++kh) {
                const float* xrow = &xs[c][prow + kh][pcol];
                float4 xa = *(const float4*)xrow;
                float4 xb = *(const float4*)(xrow + 4);
                float2 xc = *(const float2*)(xrow + 8);
                float xr[10] = {xa.x, xa.y, xa.z, xa.w,
                                xb.x, xb.y, xb.z, xb.w, xc.x, xc.y};
#pragma unroll
                for (int kw = 0; kw < 3; ++kw) {
                    float4 wv = *(const float4*)&ws[c][kh * 3 + kw][ocg * 4];
                    float wr[4] = {wv.x, wv.y, wv.z, wv.w};
#pragma unroll
                    for (int o = 0; o < 4; ++o)
#pragma unroll
                        for (int p = 0; p < 8; ++p)
                            acc[o][p] = fmaf(wr[o], xr[p + kw], acc[o][p]);
                }
            }
        }
        if (tid < CC * 16) {
            const int c = tid >> 4;
            const int g = tid & 15;
            const int hr = g >> 1;
            const int hcb = (g & 1) * 8;
            unsigned rm[3];
#pragma unroll
            for (int kh = 0; kh < 3; ++kh) {
                const float* xrow = &xs[c][hr + kh][hcb];
                float4 xa = *(const float4*)xrow;
                float4 xb = *(const float4*)(xrow + 4);
                float2 xc = *(const float2*)(xrow + 8);
                unsigned m = 0;
                m |= (xa.x == 0.0f) ? 1u : 0u;
                m |= (xa.y == 0.0f) ? 2u : 0u;
                m |= (xa.z == 0.0f) ? 4u : 0u;
                m |= (xa.w == 0.0f) ? 8u : 0u;
                m |= (xb.x == 0.0f) ? 16u : 0u;
                m |= (xb.y == 0.0f) ? 32u : 0u;
                m |= (xb.z == 0.0f) ? 64u : 0u;
                m |= (xb.w == 0.0f) ? 128u : 0u;
                m |= (xc.x == 0.0f) ? 256u : 0u;
                m |= (xc.y == 0.0f) ? 512u : 0u;
                rm[kh] = m;
            }
            const int cg = cbase + c;
            const unsigned inc = (unsigned)n0[cg];
            const int ec = exCnt[cg];
#pragma unroll
            for (int j = 0; j < 8; ++j) {
                unsigned m9 = ((rm[0] >> j) & 7u)
                            | (((rm[1] >> j) & 7u) << 3)
                            | (((rm[2] >> j) & 7u) << 6);
                atomicAdd(&hist_s[cg * 10 + __popc(m9)], inc);
                for (int e = 0; e < ec; ++e) {
                    unsigned wz = (unsigned)exMask[cg * 64 + e];
                    atomicAdd(&hist_s[cg * 10 + __popc(m9 | wz)], 1u);
                }
            }
        }
    }
#pragma unroll
    for (int o = 0; o < 4; ++o) {
        const int oc = ocg * 4 + o;
        const float bv = bias[oc];
        float4 v0, v1;
        v0.x = acc[o][0] + bv; v0.y = acc[o][1] + bv;
        v0.z = acc[o][2] + bv; v0.w = acc[o][3] + bv;
        v1.x = acc[o][4] + bv; v1.y = acc[o][5] + bv;
        v1.z = acc[o][6] + bv; v1.w = acc[o][7] + bv;
        float* dst = &out[(((long)b * On + oc) * Hn + (h0 + prow)) * Wn + w0 + pcol];
        *(float4*)dst = v0;
        *(float4*)(dst + 4) = v1;
    }
    __syncthreads();
    for (int i = tid; i < HIST_N; i += 256)
        atomicAdd(&hist[i], (float)hist_s[i]);
}

// ---------------- host ----------------
extern "C" void kernel_launch(void* const* d_in, const int* in_sizes, int n_in,
                              void* d_out, int out_size, void* d_ws, size_t ws_size,
                              hipStream_t stream) {
    const float* x    = (const float*)d_in[0];
    const float* wt   = (const float*)d_in[1];
    const float* bias = (const float*)d_in[2];
    float* out  = (float*)d_out;
    float* hist = out + CONV_ELEMS;

    if (ws_size >= NEED_WS) {
        ushort* xh  = (ushort*)d_ws;
        ushort* wb2 = xh + XT_ELEMS;
        void* ka[] = {(void*)&x, (void*)&wt, (void*)&xh, (void*)&wb2,
                      (void*)&bias, (void*)&out, (void*)&hist};
        hipError_t e = hipLaunchCooperativeKernel((const void*)fused_kernel,
                                                  dim3(MAIN_GRID), dim3(256),
                                                  ka, 0, stream);
        if (e != hipSuccess) {                    // deterministic fallback: r15 path
            (void)hipGetLastError();
            prep_kernel<<<PREP_GRID, 256, 0, stream>>>(x, wt, xh, wb2, hist);
            conv_kernel<<<MAIN_GRID, 256, 0, stream>>>(xh, wb2, bias, x, wt, out, hist);
        }
    } else {
        int* n0     = (int*)d_ws;
        int* exCnt  = n0 + 64;
        int* exMask = n0 + 128;
        setup_fb_kernel<<<1, 64, 0, stream>>>(wt, hist, n0, exCnt, exMask);
        conv_hist_kernel<<<Bn * 98, 256, 0, stream>>>(x, wt, bias, out, hist,
                                                      n0, exCnt, exMask);
    }
}

// Round 17
// 38.685 us; speedup vs baseline: 5.4506x; 5.4506x over previous
//
#include <hip/hip_runtime.h>

typedef __attribute__((ext_vector_type(8))) short bf16x8;
typedef __attribute__((ext_vector_type(4))) float f32x4;

namespace {
constexpr int Bn = 8, Cn = 64, On = 64, Hn = 112, Wn = 112;
constexpr long CONV_ELEMS = (long)Bn * On * Hn * Wn;     // 6422528
constexpr int HP = 114, WP = 114;                        // padded dims (halo)
constexpr long XT_ELEMS = (long)Bn * HP * WP * Cn;       // 6653952
constexpr size_t WB2_BYTES = 4 * 18 * 64 * 8 * 2;        // 73728 (hi-only)
constexpr size_t NEED_WS = (size_t)XT_ELEMS * 2 + WB2_BYTES;
constexpr int HIST_N = Cn * 10;
constexpr int HALO_PER_B = 2 * WP * Cn + 2 * Hn * Cn;    // 28928
constexpr int HALO_ELEMS = Bn * HALO_PER_B;              // 231424
constexpr int INT_BLOCKS = Bn * Hn * 2;                  // 1792
constexpr int HALO_BLOCKS = (HALO_ELEMS + 255) / 256;    // 904
constexpr int WSETUP_BLOCKS = 64;
constexpr int PREP_GRID = WSETUP_BLOCKS + INT_BLOCKS + HALO_BLOCKS;   // 2760
constexpr int CONV_BLOCKS = Bn * 98;                     // 784
constexpr int HIST_BLOCKS = Bn * Cn;                     // 512
constexpr int MAIN_GRID = CONV_BLOCKS + HIST_BLOCKS;     // 1296 (5.06 blocks/CU)
}

__device__ __forceinline__ ushort f2bf(float v) {        // RNE float->bf16 bits
    unsigned u = __float_as_uint(v);
    return (ushort)((u + 0x7fffu + ((u >> 16) & 1u)) >> 16);
}

// ======== prep: [0,64) wb2 + hist-zero | x->bf16 interior | halo-zero ========
// (r15-verified, 38.8us total). Cooperative fusion (r16) regressed 5.4x:
// grid-stride prep under a 1296-block coop grid serialized the BW phase.
__global__ __launch_bounds__(256) void prep_kernel(
    const float* __restrict__ x, const float* __restrict__ wt,
    ushort* __restrict__ xh, ushort* __restrict__ wb2, float* __restrict__ hist)
{
    __shared__ __align__(16) char smem[14592];
    const int bx = blockIdx.x, tid = threadIdx.x;

    if (bx < WSETUP_BLOCKS) {
        // wb2 flat = ((g*18+k)*64+lane)*8+j : oc-group g, k-step k, lane -> its
        // exact MFMA B-fragment. HI ONLY (r12: error budget ~0.09 >> added ~6e-3).
        const int bw = bx;
        for (int i = tid; i < 576; i += 256) {
            int flat = bw * 576 + i;
            int g = flat / 9216;                  // 18*64*8
            int rem = flat - g * 9216;
            int k = rem >> 9;
            int rem2 = rem & 511;
            int lane = rem2 >> 3, j = rem2 & 7;
            int kk = k * 32 + (lane >> 4) * 8 + j;
            int kp = kk >> 6, cc = kk & 63;
            wb2[flat] = f2bf(wt[((g * 16 + (lane & 15)) * Cn + cc) * 9 + kp]);
        }
        if (bw == 0)                              // hist zero (stream-ordered
            for (int i = tid; i < HIST_N; i += 256) hist[i] = 0.0f;   // before conv)
        return;
    }

    int bx2 = bx - WSETUP_BLOCKS;
    if (bx2 < INT_BLOCKS) {          // x (NCHW fp32) -> xh [b][h+1][w+1][c] bf16
        auto ls = reinterpret_cast<float(*)[57]>(smem);   // [64][57]
        const int b = bx2 / 224;
        const int rem = bx2 - b * 224;
        const int h = rem >> 1;
        const int w0 = (rem & 1) * 56;
        for (int i = tid; i < 64 * 56; i += 256) {
            int c = i / 56, w = i - c * 56;
            ls[c][w] = x[(((long)b * Cn + c) * Hn + h) * Wn + w0 + w];
        }
        __syncthreads();
        for (int i = tid; i < 56 * 64; i += 256) {
            int w = i >> 6, c = i & 63;
            xh[(((long)b * HP + h + 1) * WP + (w0 + w + 1)) * 64 + c] = f2bf(ls[c][w]);
        }
        return;
    }
    bx2 -= INT_BLOCKS;               // halo-zero
    int idx = bx2 * 256 + tid;
    if (idx < HALO_ELEMS) {
        int b = idx / HALO_PER_B;
        int r = idx - b * HALO_PER_B;
        int h, w, cc;
        if (r < WP * Cn)                    { h = 0;      w = r / Cn;               cc = r & 63; }
        else if (r < 2 * WP * Cn)           { int q = r - WP * Cn; h = HP - 1; w = q / Cn; cc = q & 63; }
        else if (r < 2 * WP * Cn + Hn * Cn) { int q = r - 2 * WP * Cn; h = 1 + q / Cn; w = 0; cc = q & 63; }
        else                                { int q = r - 2 * WP * Cn - Hn * Cn; h = 1 + q / Cn; w = WP - 1; cc = q & 63; }
        xh[((long)(b * HP + h) * WP + w) * 64 + cc] = 0;
    }
}

// ======== main: [0,784) conv | [784,1296) hist (register-mask, x is L3-warm) ========
__global__ __launch_bounds__(256, 6) void conv_kernel(
    const ushort* __restrict__ xh, const ushort* __restrict__ wb2,
    const float* __restrict__ bias, const float* __restrict__ x,
    const float* __restrict__ wt, float* __restrict__ out, float* __restrict__ hist)
{
    __shared__ __align__(16) char smem[23040];
    const int tid = threadIdx.x;

    if (blockIdx.x >= CONV_BLOCKS) {
        // ---- hist for plane (b,c): register-mask structure (r14), atomicAdd out ----
        unsigned* exm  = reinterpret_cast<unsigned*>(smem);          // [64]
        int*      meta = reinterpret_cast<int*>(smem + 256);         // n0, anyEx
        unsigned* wsum = reinterpret_cast<unsigned*>(smem + 264);    // [4][5]
        unsigned* corr = reinterpret_cast<unsigned*>(smem + 352);    // [10]
        const int hb = (int)blockIdx.x - CONV_BLOCKS;
        const int b = hb >> 6, c = hb & 63;
        if (tid < 10) corr[tid] = 0u;
        if (tid < 64) {                           // wave 0: weight-zero scan for c
            unsigned m = 0;
#pragma unroll
            for (int kp = 0; kp < 9; ++kp)
                if (wt[(tid * Cn + c) * 9 + kp] == 0.0f) m |= 1u << kp;
            exm[tid] = m;
            unsigned long long nz = __ballot(m == 0u);
            if (tid == 0) { meta[0] = (int)__popcll(nz); meta[1] = (nz != ~0ull); }
        }
        __syncthreads();

        const int h = tid >> 7;                   // waves 0,1 -> h=0; 2,3 -> h=1
        const int r = tid & 127;                  // row (active if < 112)
        unsigned pk0 = 0, pk1 = 0;                // bins 0-4 / 5-9, 6-bit fields
        if (r < Hn) {
            const float* xp = x + ((long)b * Cn + c) * (Hn * Wn);
            auto rowmask = [&](int row) -> unsigned long long {
                if ((unsigned)row >= (unsigned)Hn) return (1ull << 58) - 1ull;
                const float* rp = xp + row * Wn;
                unsigned long long m;
                if (h == 0) {
                    m = 1ull;                     // col -1 pad (bit 0)
#pragma unroll
                    for (int q = 0; q < 14; ++q) {
                        float4 v = *(const float4*)(rp + 4 * q);
                        unsigned nib = (unsigned)(v.x == 0.0f) | ((unsigned)(v.y == 0.0f) << 1)
                                     | ((unsigned)(v.z == 0.0f) << 2) | ((unsigned)(v.w == 0.0f) << 3);
                        m |= (unsigned long long)nib << (4 * q + 1);
                    }
                    m |= (unsigned long long)(rp[56] == 0.0f) << 57;
                } else {
                    m = (rp[55] == 0.0f) ? 1ull : 0ull;   // col 55 (bit 0)
#pragma unroll
                    for (int q = 0; q < 14; ++q) {
                        float4 v = *(const float4*)(rp + 56 + 4 * q);
                        unsigned nib = (unsigned)(v.x == 0.0f) | ((unsigned)(v.y == 0.0f) << 1)
                                     | ((unsigned)(v.z == 0.0f) << 2) | ((unsigned)(v.w == 0.0f) << 3);
                        m |= (unsigned long long)nib << (4 * q + 1);
                    }
                    m |= 1ull << 57;              // col 112 pad
                }
                return m;
            };
            unsigned long long Tm = rowmask(r - 1);
            unsigned long long Mm = rowmask(r);
            unsigned long long Bm = rowmask(r + 1);
#pragma unroll
            for (int i = 0; i < 56; ++i) {
                int z = __popc((unsigned)(Tm >> i) & 7u) + __popc((unsigned)(Mm >> i) & 7u)
                      + __popc((unsigned)(Bm >> i) & 7u);
                if (z < 5) pk0 += 1u << (6 * z); else pk1 += 1u << (6 * (z - 5));
            }
            if (meta[1]) {                        // exact-zero weights (never taken)
                for (int i = 0; i < 56; ++i) {
                    unsigned m9 = ((unsigned)(Tm >> i) & 7u)
                                | (((unsigned)(Mm >> i) & 7u) << 3)
                                | (((unsigned)(Bm >> i) & 7u) << 6);
                    for (int oc = 0; oc < 64; ++oc)
                        if (exm[oc]) atomicAdd(&corr[__popc(m9 | exm[oc])], 1u);
                }
            }
        }
        // 6-bit fields -> 5 u32 of 2x16-bit fields, wave shuffle-reduce
        unsigned s0 = (pk0 & 63u)       | ((pk0 >> 6 & 63u) << 16);
        unsigned s1 = (pk0 >> 12 & 63u) | ((pk0 >> 18 & 63u) << 16);
        unsigned s2 = (pk0 >> 24 & 63u) | ((pk1 & 63u) << 16);
        unsigned s3 = (pk1 >> 6 & 63u)  | ((pk1 >> 12 & 63u) << 16);
        unsigned s4 = (pk1 >> 18 & 63u) | ((pk1 >> 24 & 63u) << 16);
#pragma unroll
        for (int l = 1; l < 64; l <<= 1) {
            s0 += __shfl_xor(s0, l); s1 += __shfl_xor(s1, l);
            s2 += __shfl_xor(s2, l); s3 += __shfl_xor(s3, l);
            s4 += __shfl_xor(s4, l);
        }
        const int wv = tid >> 6;
        if ((tid & 63) == 0) {
            wsum[wv * 5 + 0] = s0; wsum[wv * 5 + 1] = s1; wsum[wv * 5 + 2] = s2;
            wsum[wv * 5 + 3] = s3; wsum[wv * 5 + 4] = s4;
        }
        __syncthreads();
        if (tid < 10) {
            unsigned tot = 0;
#pragma unroll
            for (int w2 = 0; w2 < 4; ++w2)
                tot += (wsum[w2 * 5 + (tid >> 1)] >> ((tid & 1) * 16)) & 0xffffu;
            atomicAdd(&hist[c * 10 + tid], (float)(tot * (unsigned)meta[0] + corr[tid]));
        }
        return;
    }

    // -------------------- conv path (r12 body) --------------------
    ushort* xs = (ushort*)smem;                   // 10*18 rows * 128 B
    int bid = (int)blockIdx.x;
    bid = (bid & 7) * 98 + (bid >> 3);            // XCD swizzle (784 % 8 == 0)
    const int b = bid / 98;
    const int t = bid - b * 98;
    const int h0 = (t / 7) * 8, w0 = (t % 7) * 16;
    const int lane = tid & 63, wvi = tid >> 6;
    const int l15 = lane & 15, lg = lane >> 4;
    const int pxh = wvi >> 1, och = wvi & 1;

    // stage 1440 16-B chunks: physical chunk p holds logical p ^ (wl&7)
    const ushort* xbase = xh + (long)((b * HP + h0) * WP + w0) * 64;
#pragma unroll
    for (int it = 0; it < 6; ++it) {
        int F = it * 256 + tid;
        if (F < 1440) {
            int R = F >> 3, p = F & 7;
            int hl = R / 18, wl = R - hl * 18;
            bf16x8 v = *(const bf16x8*)(xbase + (hl * WP + wl) * 64 + (p ^ (wl & 7)) * 8);
            *(bf16x8*)(xs + F * 8) = v;
        }
    }
    __syncthreads();

    const ushort* Bw0 = wb2 + (((och * 2 + 0) * 1152 + lane) << 3);  // 1152=18*64
    const ushort* Bw1 = wb2 + (((och * 2 + 1) * 1152 + lane) << 3);
    f32x4 acc[4][2];
#pragma unroll
    for (int a = 0; a < 4; ++a)
#pragma unroll
        for (int j = 0; j < 2; ++j) acc[a][j] = (f32x4){0.f, 0.f, 0.f, 0.f};

    auto lda = [&](int k, bf16x8* A) {
        int kp = k >> 1, ch = k & 1;
        int dh = kp / 3, dw = kp - 3 * dh;
        int wl = l15 + dw;
        int rowb = pxh * 9216 + dh * 2304 + wl * 128;
        int colb = ((lg + 4 * ch) << 4) ^ ((wl & 7) << 4);
#pragma unroll
        for (int a = 0; a < 4; ++a)
            A[a] = *(const bf16x8*)((const char*)xs + a * 2304 + rowb + colb);
    };

    bf16x8 AX[4], AY[4], BX0, BX1, BY0, BY1;
    lda(0, AX);
    BX0 = *(const bf16x8*)(Bw0 + 0 * 512);
    BX1 = *(const bf16x8*)(Bw1 + 0 * 512);

#pragma unroll 1
    for (int t2 = 0; t2 < 9; ++t2) {
        BY0 = *(const bf16x8*)(Bw0 + (2 * t2 + 1) * 512);
        BY1 = *(const bf16x8*)(Bw1 + (2 * t2 + 1) * 512);
        lda(2 * t2 + 1, AY);
#pragma unroll
        for (int a = 0; a < 4; ++a)
            acc[a][0] = __builtin_amdgcn_mfma_f32_16x16x32_bf16(AX[a], BX0, acc[a][0], 0, 0, 0);
#pragma unroll
        for (int a = 0; a < 4; ++a)
            acc[a][1] = __builtin_amdgcn_mfma_f32_16x16x32_bf16(AX[a], BX1, acc[a][1], 0, 0, 0);
        const int kn = (t2 < 8) ? 2 * t2 + 2 : 17;
        BX0 = *(const bf16x8*)(Bw0 + kn * 512);
        BX1 = *(const bf16x8*)(Bw1 + kn * 512);
        lda(kn, AX);
#pragma unroll
        for (int a = 0; a < 4; ++a)
            acc[a][0] = __builtin_amdgcn_mfma_f32_16x16x32_bf16(AY[a], BY0, acc[a][0], 0, 0, 0);
#pragma unroll
        for (int a = 0; a < 4; ++a)
            acc[a][1] = __builtin_amdgcn_mfma_f32_16x16x32_bf16(AY[a], BY1, acc[a][1], 0, 0, 0);
    }

    // D mapping: col(lane&15)=oc, row=(lane>>4)*4+reg = w-offset
#pragma unroll
    for (int j = 0; j < 2; ++j) {
        const int oc = och * 32 + j * 16 + l15;
        const float bv = bias[oc];
#pragma unroll
        for (int a = 0; a < 4; ++a) {
            const int hr = h0 + pxh * 4 + a;
            float4 st = {acc[a][j].x + bv, acc[a][j].y + bv,
                         acc[a][j].z + bv, acc[a][j].w + bv};
            *reinterpret_cast<float4*>(
                out + (((long)b * On + oc) * Hn + hr) * Wn + w0 + lg * 4) = st;
        }
    }
}

// ---------------- fallback (fp32, round-2) — only if ws too small ----------------
namespace fb {
constexpr int TH = 8, TW = 16, CC = 8, NCH = Cn / CC;
constexpr int XROWS = TH + 2, XCOLS = TW + 2, XSTR = 20, WPAD = 68;
}
__global__ void setup_fb_kernel(const float* __restrict__ wt, float* __restrict__ hist,
                                int* __restrict__ n0, int* __restrict__ exCnt,
                                int* __restrict__ exMask) {
    int c = threadIdx.x;
    if (c >= Cn) return;
    int cnt0 = 0, ce = 0;
    for (int oc = 0; oc < On; ++oc) {
        unsigned m = 0;
        const float* wp = wt + (oc * Cn + c) * 9;
        for (int k = 0; k < 9; ++k)
            if (wp[k] == 0.0f) m |= (1u << k);
        if (m == 0u) ++cnt0;
        else exMask[c * 64 + (ce++)] = (int)m;
    }
    n0[c] = cnt0;
    exCnt[c] = ce;
    for (int j = 0; j < 10; ++j) hist[c * 10 + j] = 0.0f;
}
__global__ __launch_bounds__(256, 4) void conv_hist_kernel(
    const float* __restrict__ x, const float* __restrict__ wt,
    const float* __restrict__ bias, float* __restrict__ out,
    float* __restrict__ hist, const int* __restrict__ n0,
    const int* __restrict__ exCnt, const int* __restrict__ exMask)
{
    using namespace fb;
    __shared__ __align__(16) float xs[CC][XROWS][XSTR];
    __shared__ __align__(16) float ws[CC][9][WPAD];
    __shared__ unsigned hist_s[HIST_N];
    const int tid = threadIdx.x;
    const int bx = blockIdx.x;
    const int b = bx / 98;
    const int tt = bx - b * 98;
    const int h0 = (tt / 7) * TH;
    const int w0 = (tt % 7) * TW;
    const int ocg = tid >> 4, pg = tid & 15;
    const int prow = pg >> 1, pcol = (pg & 1) * 8;
    float acc[4][8];
#pragma unroll
    for (int o = 0; o < 4; ++o)
#pragma unroll
        for (int p = 0; p < 8; ++p) acc[o][p] = 0.0f;
    for (int i = tid; i < HIST_N; i += 256) hist_s[i] = 0u;
#pragma unroll 1
    for (int cc = 0; cc < NCH; ++cc) {
        const int cbase = cc * CC;
        __syncthreads();
#pragma unroll 1
        for (int i = tid; i < CC * XROWS * XCOLS; i += 256) {
            int c = i / (XROWS * XCOLS);
            int r = (i - c * XROWS * XCOLS) / XCOLS;
            int cl = i - c * XROWS * XCOLS - r * XCOLS;
            int gr = h0 - 1 + r, gc = w0 - 1 + cl;
            float v = 0.0f;
            if ((unsigned)gr < (unsigned)Hn && (unsigned)gc < (unsigned)Wn)
                v = x[(((long)b * Cn + cbase + c) * Hn + gr) * Wn + gc];
            xs[c][r][cl] = v;
        }
#pragma unroll 1
        for (int i = tid; i < On * CC * 9; i += 256) {
            int oc = i / (CC * 9);
            int j = i - oc * (CC * 9);
            int c = j / 9;
            int k = j - c * 9;
            ws[c][k][oc] = wt[(oc * Cn + cbase + c) * 9 + k];
        }
        __syncthreads();
#pragma unroll 1
        for (int c = 0; c < CC; ++c) {
#pragma unroll
            for (int kh = 0; kh < 3; ++kh) {
                const float* xrow = &xs[c][prow + kh][pcol];
                float4 xa = *(const float4*)xrow;
                float4 xb = *(const float4*)(xrow + 4);
                float2 xc = *(const float2*)(xrow + 8);
                float xr[10] = {xa.x, xa.y, xa.z, xa.w,
                                xb.x, xb.y, xb.z, xb.w, xc.x, xc.y};
#pragma unroll
                for (int kw = 0; kw < 3; ++kw) {
                    float4 wv = *(const float4*)&ws[c][kh * 3 + kw][ocg * 4];
                    float wr[4] = {wv.x, wv.y, wv.z, wv.w};
#pragma unroll
                    for (int o = 0; o < 4; ++o)
#pragma unroll
                        for (int p = 0; p < 8; ++p)
                            acc[o][p] = fmaf(wr[o], xr[p + kw], acc[o][p]);
                }
            }
        }
        if (tid < CC * 16) {
            const int c = tid >> 4;
            const int g = tid & 15;
            const int hr = g >> 1;
            const int hcb = (g & 1) * 8;
            unsigned rm[3];
#pragma unroll
            for (int kh = 0; kh < 3; ++kh) {
                const float* xrow = &xs[c][hr + kh][hcb];
                float4 xa = *(const float4*)xrow;
                float4 xb = *(const float4*)(xrow + 4);
                float2 xc = *(const float2*)(xrow + 8);
                unsigned m = 0;
                m |= (xa.x == 0.0f) ? 1u : 0u;
                m |= (xa.y == 0.0f) ? 2u : 0u;
                m |= (xa.z == 0.0f) ? 4u : 0u;
                m |= (xa.w == 0.0f) ? 8u : 0u;
                m |= (xb.x == 0.0f) ? 16u : 0u;
                m |= (xb.y == 0.0f) ? 32u : 0u;
                m |= (xb.z == 0.0f) ? 64u : 0u;
                m |= (xb.w == 0.0f) ? 128u : 0u;
                m |= (xc.x == 0.0f) ? 256u : 0u;
                m |= (xc.y == 0.0f) ? 512u : 0u;
                rm[kh] = m;
            }
            const int cg = cbase + c;
            const unsigned inc = (unsigned)n0[cg];
            const int ec = exCnt[cg];
#pragma unroll
            for (int j = 0; j < 8; ++j) {
                unsigned m9 = ((rm[0] >> j) & 7u)
                            | (((rm[1] >> j) & 7u) << 3)
                            | (((rm[2] >> j) & 7u) << 6);
                atomicAdd(&hist_s[cg * 10 + __popc(m9)], inc);
                for (int e = 0; e < ec; ++e) {
                    unsigned wz = (unsigned)exMask[cg * 64 + e];
                    atomicAdd(&hist_s[cg * 10 + __popc(m9 | wz)], 1u);
                }
            }
        }
    }
#pragma unroll
    for (int o = 0; o < 4; ++o) {
        const int oc = ocg * 4 + o;
        const float bv = bias[oc];
        float4 v0, v1;
        v0.x = acc[o][0] + bv; v0.y = acc[o][1] + bv;
        v0.z = acc[o][2] + bv; v0.w = acc[o][3] + bv;
        v1.x = acc[o][4] + bv; v1.y = acc[o][5] + bv;
        v1.z = acc[o][6] + bv; v1.w = acc[o][7] + bv;
        float* dst = &out[(((long)b * On + oc) * Hn + (h0 + prow)) * Wn + w0 + pcol];
        *(float4*)dst = v0;
        *(float4*)(dst + 4) = v1;
    }
    __syncthreads();
    for (int i = tid; i < HIST_N; i += 256)
        atomicAdd(&hist[i], (float)hist_s[i]);
}

// ---------------- host ----------------
extern "C" void kernel_launch(void* const* d_in, const int* in_sizes, int n_in,
                              void* d_out, int out_size, void* d_ws, size_t ws_size,
                              hipStream_t stream) {
    const float* x    = (const float*)d_in[0];
    const float* wt   = (const float*)d_in[1];
    const float* bias = (const float*)d_in[2];
    float* out  = (float*)d_out;
    float* hist = out + CONV_ELEMS;

    if (ws_size >= NEED_WS) {
        ushort* xh  = (ushort*)d_ws;
        ushort* wb2 = xh + XT_ELEMS;
        prep_kernel<<<PREP_GRID, 256, 0, stream>>>(x, wt, xh, wb2, hist);
        conv_kernel<<<MAIN_GRID, 256, 0, stream>>>(xh, wb2, bias, x, wt, out, hist);
    } else {
        int* n0     = (int*)d_ws;
        int* exCnt  = n0 + 64;
        int* exMask = n0 + 128;
        setup_fb_kernel<<<1, 64, 0, stream>>>(wt, hist, n0, exCnt, exMask);
        conv_hist_kernel<<<Bn * 98, 256, 0, stream>>>(x, wt, bias, out, hist,
                                                      n0, exCnt, exMask);
    }
}